// Round 8
// baseline (113702.722 us; speedup 1.0000x reference)
//
#include <hip/hip_runtime.h>
#include <cstdint>
#include <cstddef>

#define TT 514

typedef unsigned short u16;
typedef short short8 __attribute__((ext_vector_type(8)));
typedef float f32x4 __attribute__((ext_vector_type(4)));

__device__ __forceinline__ float bf2f(u16 u) {
  union { unsigned i; float f; } x; x.i = ((unsigned)u) << 16; return x.f;
}
__device__ __forceinline__ u16 f2bf(float f) {
  union { float f; unsigned i; } x; x.f = f;
  unsigned r = x.i + 0x7fffu + ((x.i >> 16) & 1u);
  return (u16)(r >> 16);
}
__device__ __forceinline__ float sigm(float x) { return 1.f / (1.f + expf(-x)); }
__device__ __forceinline__ f32x4 mfma16(short8 a, short8 b, f32x4 c) {
  return __builtin_amdgcn_mfma_f32_16x16x32_bf16(a, b, c, 0, 0, 0);
}
__device__ __forceinline__ void sb_set(float* sb, int k) {
  __hip_atomic_store(sb + k, 1.0f, __ATOMIC_RELAXED, __HIP_MEMORY_SCOPE_AGENT);
}

// ---- diagnostics: write an error-code into an out0 slot (f32 now!) ----
__global__ void diag_kernel(float* __restrict__ out, float code, int slot) {
  if (threadIdx.x == 0 && blockIdx.x == 0) out[slot] = code;
}
__global__ void verify_kernel(const float* __restrict__ sb, float* __restrict__ out) {
  if (threadIdx.x == 0 && blockIdx.x == 0) {
    for (int k = 0; k < 6; ++k) {
      float v = __hip_atomic_load(sb + k, __ATOMIC_RELAXED, __HIP_MEMORY_SCOPE_AGENT);
      if (v != 1.0f) out[9 + k] = 4096.f + (float)k * 256.f;
    }
  }
}

// ---------------- embedding + BOS/EOS -> x bf16, layout [t][b][d] ----------------
__global__ __launch_bounds__(256) void embed_kernel(const int* __restrict__ words,
                                                    const float* __restrict__ E,
                                                    const float* __restrict__ bos,
                                                    const float* __restrict__ eos,
                                                    u16* __restrict__ xb16,
                                                    float* __restrict__ sb) {
  int bid = blockIdx.x;           // t*4 + b
  int t = bid >> 2, b = bid & 3;
  const float* src;
  if (t == 0) src = bos;
  else if (t == TT - 1) src = eos;
  else { int v = words[b * 512 + (t - 1)]; src = E + (size_t)v * 512; }
  for (int i = threadIdx.x; i < 512; i += 256)
    xb16[(size_t)bid * 512 + i] = f2bf(src[i]);
  if (bid == TT * 4 - 1 && threadIdx.x == 0) sb_set(sb, 0);
}

// ---- XW[dir][t*4+b][16384] = (x @ W_in + bias), bf16. K=512, M=2056, N=16384 ----
__global__ __launch_bounds__(256) void xw_gemm(const u16* __restrict__ Af,
                                               const u16* __restrict__ Ab,
                                               const float* __restrict__ Win_g,
                                               const float* __restrict__ bias_g,
                                               u16* __restrict__ XW,
                                               float* __restrict__ sb,
                                               int layer, int sbslot) {
  int bid = blockIdx.x;
  int dir = bid / (17 * 128);
  int rem = bid % (17 * 128);
  int mb = rem / 128, nb = rem % 128;
  const u16* A = dir ? Ab : Af;
  const float* B = Win_g + (size_t)(dir * 2 + layer) * 512 * 16384;
  const float* bias = bias_g + (size_t)(dir * 2 + layer) * 16384;
  u16* out = XW + (size_t)dir * 2056 * 16384;
  int m0 = mb * 128, n0 = nb * 128;
  __shared__ char lds[2 * 128 * 80];
  char* At = lds;
  char* Bt = lds + 128 * 80;
  int tid = threadIdx.x, wv = tid >> 6, ln = tid & 63;
  int wr = wv >> 1, wc = wv & 1;
  f32x4 acc[4][4];
  #pragma unroll
  for (int i = 0; i < 4; ++i)
    #pragma unroll
    for (int j = 0; j < 4; ++j) acc[i][j] = (f32x4){0.f, 0.f, 0.f, 0.f};
  for (int k0 = 0; k0 < 512; k0 += 32) {
    __syncthreads();
    {
      int r = tid >> 2, kq = (tid & 3) * 8;
      for (int rr = r; rr < 128; rr += 64) {
        int grow = m0 + rr; if (grow >= 2056) grow = 2055;
        short8 va = *(const short8*)(A + (size_t)grow * 512 + k0 + kq);
        *(short8*)(At + rr * 80 + kq * 2) = va;
      }
      int kk = tid >> 3, nq = (tid & 7) * 16;
      const float* bp = B + (size_t)(k0 + kk) * 16384 + n0 + nq;
      #pragma unroll
      for (int e = 0; e < 16; ++e)
        *(u16*)(Bt + (nq + e) * 80 + kk * 2) = f2bf(bp[e]);
    }
    __syncthreads();
    int lr = ln & 15, kq2 = (ln >> 4) * 8;
    short8 af[4], bf[4];
    #pragma unroll
    for (int i = 0; i < 4; ++i) {
      af[i] = *(const short8*)(At + (wr * 64 + i * 16 + lr) * 80 + kq2 * 2);
      bf[i] = *(const short8*)(Bt + (wc * 64 + i * 16 + lr) * 80 + kq2 * 2);
    }
    #pragma unroll
    for (int i = 0; i < 4; ++i)
      #pragma unroll
      for (int j = 0; j < 4; ++j) acc[i][j] = mfma16(af[i], bf[j], acc[i][j]);
  }
  int cc = ln & 15, rq = (ln >> 4) * 4;
  #pragma unroll
  for (int i = 0; i < 4; ++i)
    #pragma unroll
    for (int j = 0; j < 4; ++j) {
      int m = m0 + wr * 64 + i * 16 + rq;
      int v = n0 + wc * 64 + j * 16 + cc;
      float bv = bias[v];
      #pragma unroll
      for (int r2 = 0; r2 < 4; ++r2)
        if (m + r2 < 2056) out[(size_t)(m + r2) * 16384 + v] = f2bf(acc[i][j][r2] + bv);
    }
  if (bid == 2 * 17 * 128 - 1 && tid == 0) sb_set(sb, sbslot);
}

// -------- per-step kernel 1: gates = h @ W_state (f32 VALU dot) + elementwise --------
__global__ __launch_bounds__(256) void gates_kernel(
    const float* __restrict__ Wst_g, const u16* __restrict__ XW,
    const float* __restrict__ hbuf, float* __restrict__ cbuf,
    float* __restrict__ abuf, int layer, int s) {
  __shared__ float h_lds[512 * 4];       // [k][b]
  __shared__ float g_lds[4 * 32 * 4];    // [gate][chl][b]
  int tid = threadIdx.x;
  int dir = (int)blockIdx.x >> 7, wgd = (int)blockIdx.x & 127;
  int t = dir ? (TT - 1 - s) : s;
  int dl = dir * 2 + layer;
  const float* W = Wst_g + (size_t)dl * 512 * 16384;
  for (int i = tid; i < 2048; i += 256) {
    int b = i >> 9, k = i & 511;
    h_lds[k * 4 + b] = hbuf[dir * 2048 + i];
  }
  __syncthreads();
  {
    int chl = tid & 31, g = (tid >> 5) & 3, bp = tid >> 7;
    int ch = wgd * 32 + chl;
    const float* wp = W + g * 4096 + ch;
    float a0 = 0.f, a1 = 0.f;
    #pragma unroll 8
    for (int k = 0; k < 512; ++k) {
      float w = wp[(size_t)k * 16384];
      a0 = fmaf(w, h_lds[k * 4 + bp * 2], a0);
      a1 = fmaf(w, h_lds[k * 4 + bp * 2 + 1], a1);
    }
    g_lds[(g * 32 + chl) * 4 + bp * 2] = a0;
    g_lds[(g * 32 + chl) * 4 + bp * 2 + 1] = a1;
  }
  __syncthreads();
  if (tid < 128) {
    int cl = tid >> 2, b = tid & 3;
    size_t xbase = (size_t)dir * 2056 * 16384 + ((size_t)t * 4 + b) * 16384 + wgd * 32 + cl;
    float gi = g_lds[(0 * 32 + cl) * 4 + b] + bf2f(XW[xbase]);
    float gf = g_lds[(1 * 32 + cl) * 4 + b] + bf2f(XW[xbase + 4096]);
    float gg = g_lds[(2 * 32 + cl) * 4 + b] + bf2f(XW[xbase + 8192]);
    float go = g_lds[(3 * 32 + cl) * 4 + b] + bf2f(XW[xbase + 12288]);
    int cidx = dir * 16384 + b * 4096 + wgd * 32 + cl;
    float cn = sigm(gi) * tanhf(gg) + sigm(gf) * cbuf[cidx];
    cn = fminf(3.f, fmaxf(-3.f, cn));
    cbuf[cidx] = cn;
    abuf[cidx] = sigm(go) * tanhf(cn);
  }
}

// -------- per-step kernel 2: h = clip(a @ W_proj); write hbuf + seq-out (bf16) --------
__global__ __launch_bounds__(256) void proj_kernel(
    const float* __restrict__ Wp_g, const float* __restrict__ abuf,
    float* __restrict__ hbuf, u16* __restrict__ sob_f, u16* __restrict__ sob_b,
    float* __restrict__ sb, int layer, int s, int sbslot) {
  __shared__ float a_lds[16384];         // [b][ch]
  __shared__ float part[64 * 4 * 4];     // [hl][b][kc]
  int tid = threadIdx.x;
  int dir = (int)blockIdx.x >> 3, wgp = (int)blockIdx.x & 7;
  int t = dir ? (TT - 1 - s) : s;
  int dl = dir * 2 + layer;
  const float* Wp = Wp_g + (size_t)dl * 4096 * 512;
  u16* sob = dir ? sob_b : sob_f;
  for (int i = tid; i < 16384; i += 256) a_lds[i] = abuf[dir * 16384 + i];
  __syncthreads();
  {
    int hq = (tid & 15) * 4, b = (tid >> 4) & 3, kc = tid >> 6;
    const float* wb = Wp + (size_t)kc * 1024 * 512 + wgp * 64 + hq;
    const float* ab = a_lds + b * 4096 + kc * 1024;
    float p0 = 0.f, p1 = 0.f, p2 = 0.f, p3 = 0.f;
    #pragma unroll 4
    for (int k = 0; k < 1024; ++k) {
      float4 w = *(const float4*)(wb + (size_t)k * 512);
      float av = ab[k];
      p0 = fmaf(av, w.x, p0);
      p1 = fmaf(av, w.y, p1);
      p2 = fmaf(av, w.z, p2);
      p3 = fmaf(av, w.w, p3);
    }
    part[((hq + 0) * 4 + b) * 4 + kc] = p0;
    part[((hq + 1) * 4 + b) * 4 + kc] = p1;
    part[((hq + 2) * 4 + b) * 4 + kc] = p2;
    part[((hq + 3) * 4 + b) * 4 + kc] = p3;
  }
  __syncthreads();
  {
    int hl = tid >> 2, b = tid & 3;
    float v = part[(hl * 4 + b) * 4 + 0] + part[(hl * 4 + b) * 4 + 1] +
              part[(hl * 4 + b) * 4 + 2] + part[(hl * 4 + b) * 4 + 3];
    float h = fminf(3.f, fmaxf(-3.f, v));
    int hcol = wgp * 64 + hl;
    hbuf[dir * 2048 + b * 512 + hcol] = h;
    sob[((size_t)t * 4 + b) * 512 + hcol] = f2bf(h);
  }
  if (s == TT - 1 && blockIdx.x == 15 && tid == 0) sb_set(sb, sbslot);
}

// ------- softmax-weight mixing -> f32 output + bf16 logit A (tied=[E;E] K-fold) -------
__global__ __launch_bounds__(256) void mix_kernel(const u16* __restrict__ xb,
                                                  const u16* __restrict__ s1f,
                                                  const u16* __restrict__ s1b,
                                                  const u16* __restrict__ s2f,
                                                  const u16* __restrict__ s2b,
                                                  const float* __restrict__ sv,
                                                  const float* __restrict__ gm,
                                                  float* __restrict__ out,
                                                  u16* __restrict__ logitA,
                                                  float* __restrict__ sb) {
  int m = blockIdx.x;             // b*512 + tt
  int b = m >> 9, tt = m & 511;
  int t = tt + 1;
  float v0s = sv[0], v1s = sv[1], v2s = sv[2];
  float mx = fmaxf(v0s, fmaxf(v1s, v2s));
  float e0 = expf(v0s - mx), e1 = expf(v1s - mx), e2 = expf(v2s - mx);
  float inv = 1.f / (e0 + e1 + e2);
  float w0 = e0 * inv, w1 = e1 * inv, w2 = e2 * inv;
  float g = gm[0];
  size_t base = ((size_t)t * 4 + b) * 512;
  for (int d = threadIdx.x; d < 512; d += 256) {
    float xv = bf2f(xb[base + d]);
    float a1f = bf2f(s1f[base + d]), a1b = bf2f(s1b[base + d]);
    float a2f = bf2f(s2f[base + d]), a2b = bf2f(s2b[base + d]);
    float o0 = g * (w0 * xv + w1 * a1f + w2 * (a2f + a1f));  // layer2 = raw + layer1 resid
    float o1 = g * (w0 * xv + w1 * a1b + w2 * (a2b + a1b));
    out[(size_t)m * 1024 + d] = o0;
    out[(size_t)m * 1024 + 512 + d] = o1;
    logitA[(size_t)m * 512 + d] = f2bf(o0 + o1);
  }
  if (m == 2047 && threadIdx.x == 0) sb_set(sb, 5);
}

__global__ __launch_bounds__(256) void mask_fill(float* __restrict__ out) {
  int i = blockIdx.x * 256 + threadIdx.x;
  if (i < 2048) out[2097152 + i] = 1.0f;
}

// ---- logit GEMM: C[2048][32000](f32) = A[2048][512](bf16) * E[32000][512](f32->bf16)^T ----
__global__ __launch_bounds__(256) void logit_gemm(const u16* __restrict__ A,
                                                  const float* __restrict__ E,
                                                  float* __restrict__ out) {
  int bid = blockIdx.x;
  int mb = bid / 250, nb = bid % 250;
  int m0 = mb * 128, n0 = nb * 128;
  __shared__ char lds[2 * 128 * 80];
  char* At = lds;
  char* Bt = lds + 128 * 80;
  int tid = threadIdx.x, wv = tid >> 6, ln = tid & 63;
  int wr = wv >> 1, wc = wv & 1;
  f32x4 acc[4][4];
  #pragma unroll
  for (int i = 0; i < 4; ++i)
    #pragma unroll
    for (int j = 0; j < 4; ++j) acc[i][j] = (f32x4){0.f, 0.f, 0.f, 0.f};
  for (int k0 = 0; k0 < 512; k0 += 32) {
    __syncthreads();
    int r = tid >> 2, kq = (tid & 3) * 8;
    for (int rr = r; rr < 128; rr += 64) {
      short8 va = *(const short8*)(A + (size_t)(m0 + rr) * 512 + k0 + kq);
      *(short8*)(At + rr * 80 + kq * 2) = va;
      const float* ep = E + (size_t)(n0 + rr) * 512 + k0 + kq;
      float4 ea = *(const float4*)ep;
      float4 eb = *(const float4*)(ep + 4);
      short8 vb;
      ((u16*)&vb)[0] = f2bf(ea.x); ((u16*)&vb)[1] = f2bf(ea.y);
      ((u16*)&vb)[2] = f2bf(ea.z); ((u16*)&vb)[3] = f2bf(ea.w);
      ((u16*)&vb)[4] = f2bf(eb.x); ((u16*)&vb)[5] = f2bf(eb.y);
      ((u16*)&vb)[6] = f2bf(eb.z); ((u16*)&vb)[7] = f2bf(eb.w);
      *(short8*)(Bt + rr * 80 + kq * 2) = vb;
    }
    __syncthreads();
    int lr = ln & 15, kq2 = (ln >> 4) * 8;
    short8 af[4], bf[4];
    #pragma unroll
    for (int i = 0; i < 4; ++i) {
      af[i] = *(const short8*)(At + (wr * 64 + i * 16 + lr) * 80 + kq2 * 2);
      bf[i] = *(const short8*)(Bt + (wc * 64 + i * 16 + lr) * 80 + kq2 * 2);
    }
    #pragma unroll
    for (int i = 0; i < 4; ++i)
      #pragma unroll
      for (int j = 0; j < 4; ++j) acc[i][j] = mfma16(af[i], bf[j], acc[i][j]);
  }
  int cc = ln & 15, rq = (ln >> 4) * 4;
  #pragma unroll
  for (int i = 0; i < 4; ++i)
    #pragma unroll
    for (int j = 0; j < 4; ++j) {
      int m = m0 + wr * 64 + i * 16 + rq;
      int v = n0 + wc * 64 + j * 16 + cc;
      #pragma unroll
      for (int r2 = 0; r2 < 4; ++r2)
        out[2099200 + (size_t)(m + r2) * 32000 + v] = acc[i][j][r2];
    }
}

static int map_hip_err(hipError_t e) {
  switch ((int)e) {
    case 1: return 1;
    case 2: return 2;
    case 9: return 3;
    case 98: return 4;
    case 701: return 5;
    case 719: return 6;
    case 720: return 7;
    default: return 0;
  }
}

extern "C" void kernel_launch(void* const* d_in, const int* in_sizes, int n_in,
                              void* d_out, int out_size, void* d_ws, size_t ws_size,
                              hipStream_t stream) {
  const int* words = (const int*)d_in[0];
  const float* E = (const float*)d_in[1];
  const float* bos = (const float*)d_in[2];
  const float* eos = (const float*)d_in[3];
  const float* Win = (const float*)d_in[4];
  const float* Wst = (const float*)d_in[5];
  const float* bias = (const float*)d_in[6];
  const float* Wp = (const float*)d_in[7];
  const float* sv = (const float*)d_in[8];
  const float* gm = (const float*)d_in[9];
  float* outp = (float*)d_out;

  // ---- input sanity (mismatch -> code 40960 + i*256 in out[7]) ----
  {
    int bad = -1;
    if (n_in < 10) bad = 12;
    else {
      const int expct[10] = {2048, 16384000, 512, 512, 33554432, 33554432,
                             65536, 8388608, 3, 1};
      for (int i = 0; i < 10; ++i)
        if (in_sizes[i] != expct[i]) { bad = i; break; }
    }
    if (bad < 0 && out_size != 67635200) bad = 13;
    if (bad >= 0) {
      diag_kernel<<<1, 64, 0, stream>>>(outp, 40960.f + (float)bad * 256.f, 7);
      return;
    }
  }

  char* ws = (char*)d_ws;
  size_t off = 0;
  auto nxt = [&](size_t b) { size_t r = off; off += (b + 255) & ~(size_t)255; return r; };
  u16* xb16 = (u16*)(ws + nxt(514UL * 4 * 512 * 2));
  u16* s1fb = (u16*)(ws + nxt(514UL * 4 * 512 * 2));
  u16* s1bb = (u16*)(ws + nxt(514UL * 4 * 512 * 2));
  u16* s2fb = (u16*)(ws + nxt(514UL * 4 * 512 * 2));
  u16* s2bb = (u16*)(ws + nxt(514UL * 4 * 512 * 2));
  u16* logitA = (u16*)(ws + nxt(2048UL * 512 * 2));
  size_t hbuf_off = nxt(2UL * 4 * 512 * 4);
  float* hbuf = (float*)(ws + hbuf_off);
  size_t cbuf_off = nxt(2UL * 4 * 4096 * 4);
  float* cbuf = (float*)(ws + cbuf_off);
  float* abuf = (float*)(ws + nxt(2UL * 4 * 4096 * 4));
  size_t sb_off = nxt(256);
  float* sb = (float*)(ws + sb_off);
  u16* XW = (u16*)(ws + nxt(2UL * 2056 * 16384 * 2));
  if (off > ws_size) {
    diag_kernel<<<1, 64, 0, stream>>>(outp, 49152.f, 7);
    return;
  }

  int errIdx = -1;
  hipError_t errE = hipSuccess;
  auto chk = [&](int idx) {
    hipError_t e = hipGetLastError();
    if (e != hipSuccess && errIdx < 0) { errIdx = idx; errE = e; }
  };

  hipMemsetAsync(ws + sb_off, 0, 256, stream);

  embed_kernel<<<TT * 4, 256, 0, stream>>>(words, E, bos, eos, xb16, sb);
  chk(0);

  // ================= layer 0 =================
  xw_gemm<<<2 * 17 * 128, 256, 0, stream>>>(xb16, xb16, Win, bias, XW, sb, 0, 1);
  chk(1);
  hipMemsetAsync(ws + hbuf_off, 0, 16384, stream);
  hipMemsetAsync(ws + cbuf_off, 0, 131072, stream);
  for (int s = 0; s < TT; ++s) {
    gates_kernel<<<256, 256, 0, stream>>>(Wst, XW, hbuf, cbuf, abuf, 0, s);
    proj_kernel<<<16, 256, 0, stream>>>(Wp, abuf, hbuf, s1fb, s1bb, sb, 0, s, 2);
    if (s == 0) chk(2);
  }

  // ================= layer 1 =================
  xw_gemm<<<2 * 17 * 128, 256, 0, stream>>>(s1fb, s1bb, Win, bias, XW, sb, 1, 3);
  chk(3);
  hipMemsetAsync(ws + hbuf_off, 0, 16384, stream);
  hipMemsetAsync(ws + cbuf_off, 0, 131072, stream);
  for (int s = 0; s < TT; ++s) {
    gates_kernel<<<256, 256, 0, stream>>>(Wst, XW, hbuf, cbuf, abuf, 1, s);
    proj_kernel<<<16, 256, 0, stream>>>(Wp, abuf, hbuf, s2fb, s2bb, sb, 1, s, 4);
    if (s == 0) chk(4);
  }

  mix_kernel<<<2048, 256, 0, stream>>>(xb16, s1fb, s1bb, s2fb, s2bb, sv, gm,
                                       outp, logitA, sb);
  chk(5);
  mask_fill<<<8, 256, 0, stream>>>(outp);
  chk(6);
  logit_gemm<<<4000, 256, 0, stream>>>(logitA, E, outp);
  chk(7);

  if (errIdx >= 0) {
    float code = 32768.f + (float)errIdx * 2048.f + (float)map_hip_err(errE) * 256.f;
    diag_kernel<<<1, 64, 0, stream>>>(outp, code, 7);
  }
  verify_kernel<<<1, 64, 0, stream>>>(sb, outp);
}

// Round 9
// 28741.174 us; speedup vs baseline: 3.9561x; 3.9561x over previous
//
#include <hip/hip_runtime.h>
#include <cstdint>
#include <cstddef>

#define TT 514
#define SCAN_WGS 256
#define SCAN_THR 512

typedef unsigned short u16;
typedef short short8 __attribute__((ext_vector_type(8)));
typedef short short4v __attribute__((ext_vector_type(4)));
typedef float f32x4 __attribute__((ext_vector_type(4)));

__device__ __forceinline__ float bf2f(u16 u) {
  union { unsigned i; float f; } x; x.i = ((unsigned)u) << 16; return x.f;
}
__device__ __forceinline__ u16 f2bf(float f) {
  union { float f; unsigned i; } x; x.f = f;
  unsigned r = x.i + 0x7fffu + ((x.i >> 16) & 1u);
  return (u16)(r >> 16);
}
__device__ __forceinline__ float sigm(float x) { return 1.f / (1.f + expf(-x)); }
__device__ __forceinline__ f32x4 mfma16(short8 a, short8 b, f32x4 c) {
  return __builtin_amdgcn_mfma_f32_16x16x32_bf16(a, b, c, 0, 0, 0);
}
__device__ __forceinline__ void sb_set(float* sb, int k) {
  __hip_atomic_store(sb + k, 1.0f, __ATOMIC_RELAXED, __HIP_MEMORY_SCOPE_AGENT);
}

// sense-reversal grid barrier; sticky dead-flag bailout (~1e7 spins) keeps it finite
__device__ __forceinline__ void grid_barrier(int* bar) {
  __syncthreads();
  if (threadIdx.x == 0) {
    if (__hip_atomic_load(bar + 2, __ATOMIC_RELAXED, __HIP_MEMORY_SCOPE_AGENT) == 0) {
      int g = __hip_atomic_load(bar + 1, __ATOMIC_RELAXED, __HIP_MEMORY_SCOPE_AGENT);
      int p = __hip_atomic_fetch_add(bar, 1, __ATOMIC_ACQ_REL, __HIP_MEMORY_SCOPE_AGENT);
      if (p == SCAN_WGS - 1) {
        __hip_atomic_store(bar, 0, __ATOMIC_RELAXED, __HIP_MEMORY_SCOPE_AGENT);
        __hip_atomic_fetch_add(bar + 1, 1, __ATOMIC_RELEASE, __HIP_MEMORY_SCOPE_AGENT);
      } else {
        int spins = 0;
        while (__hip_atomic_load(bar + 1, __ATOMIC_ACQUIRE, __HIP_MEMORY_SCOPE_AGENT) == g) {
          __builtin_amdgcn_s_sleep(1);
          if (++spins > 10000000) {
            __hip_atomic_store(bar + 2, 1, __ATOMIC_RELAXED, __HIP_MEMORY_SCOPE_AGENT);
            break;
          }
        }
      }
    }
  }
  __syncthreads();
}

// ---- diagnostics (f32, visible) ----
__global__ void diag_kernel(float* __restrict__ out, float code, int slot) {
  if (threadIdx.x == 0 && blockIdx.x == 0) out[slot] = code;
}
__global__ void verify_kernel(const float* __restrict__ sb, const int* __restrict__ barz,
                              float* __restrict__ out) {
  if (threadIdx.x == 0 && blockIdx.x == 0) {
    for (int k = 0; k < 6; ++k) {
      float v = __hip_atomic_load(sb + k, __ATOMIC_RELAXED, __HIP_MEMORY_SCOPE_AGENT);
      if (v != 1.0f) out[9 + k] = 4096.f + (float)k * 256.f;
    }
    if (barz[2] != 0) out[8] = 8192.f;       // layer-0 barrier bailout
    if (barz[16 + 2] != 0) out[8] = 8448.f;  // layer-1 barrier bailout
  }
}

// ---------------- embedding + BOS/EOS -> x bf16, layout [t][b][d] ----------------
__global__ __launch_bounds__(256) void embed_kernel(const int* __restrict__ words,
                                                    const float* __restrict__ E,
                                                    const float* __restrict__ bos,
                                                    const float* __restrict__ eos,
                                                    u16* __restrict__ xb16,
                                                    float* __restrict__ sb) {
  int bid = blockIdx.x;           // t*4 + b
  int t = bid >> 2, b = bid & 3;
  const float* src;
  if (t == 0) src = bos;
  else if (t == TT - 1) src = eos;
  else { int v = words[b * 512 + (t - 1)]; src = E + (size_t)v * 512; }
  for (int i = threadIdx.x; i < 512; i += 256)
    xb16[(size_t)bid * 512 + i] = f2bf(src[i]);
  if (bid == TT * 4 - 1 && threadIdx.x == 0) sb_set(sb, 0);
}

// ---- XW[dir][t*4+b][16384] = (x @ W_in + bias), bf16. K=512, M=2056, N=16384 ----
__global__ __launch_bounds__(256) void xw_gemm(const u16* __restrict__ Af,
                                               const u16* __restrict__ Ab,
                                               const float* __restrict__ Win_g,
                                               const float* __restrict__ bias_g,
                                               u16* __restrict__ XW,
                                               float* __restrict__ sb,
                                               int layer, int sbslot) {
  int bid = blockIdx.x;
  int dir = bid / (17 * 128);
  int rem = bid % (17 * 128);
  int mb = rem / 128, nb = rem % 128;
  const u16* A = dir ? Ab : Af;
  const float* B = Win_g + (size_t)(dir * 2 + layer) * 512 * 16384;
  const float* bias = bias_g + (size_t)(dir * 2 + layer) * 16384;
  u16* out = XW + (size_t)dir * 2056 * 16384;
  int m0 = mb * 128, n0 = nb * 128;
  __shared__ char lds[2 * 128 * 80];
  char* At = lds;
  char* Bt = lds + 128 * 80;
  int tid = threadIdx.x, wv = tid >> 6, ln = tid & 63;
  int wr = wv >> 1, wc = wv & 1;
  f32x4 acc[4][4];
  #pragma unroll
  for (int i = 0; i < 4; ++i)
    #pragma unroll
    for (int j = 0; j < 4; ++j) acc[i][j] = (f32x4){0.f, 0.f, 0.f, 0.f};
  for (int k0 = 0; k0 < 512; k0 += 32) {
    __syncthreads();
    {
      int r = tid >> 2, kq = (tid & 3) * 8;
      for (int rr = r; rr < 128; rr += 64) {
        int grow = m0 + rr; if (grow >= 2056) grow = 2055;
        short8 va = *(const short8*)(A + (size_t)grow * 512 + k0 + kq);
        *(short8*)(At + rr * 80 + kq * 2) = va;
      }
      int kk = tid >> 3, nq = (tid & 7) * 16;
      const float* bp = B + (size_t)(k0 + kk) * 16384 + n0 + nq;
      #pragma unroll
      for (int e = 0; e < 16; ++e)
        *(u16*)(Bt + (nq + e) * 80 + kk * 2) = f2bf(bp[e]);
    }
    __syncthreads();
    int lr = ln & 15, kq2 = (ln >> 4) * 8;
    short8 af[4], bf[4];
    #pragma unroll
    for (int i = 0; i < 4; ++i) {
      af[i] = *(const short8*)(At + (wr * 64 + i * 16 + lr) * 80 + kq2 * 2);
      bf[i] = *(const short8*)(Bt + (wc * 64 + i * 16 + lr) * 80 + kq2 * 2);
    }
    #pragma unroll
    for (int i = 0; i < 4; ++i)
      #pragma unroll
      for (int j = 0; j < 4; ++j) acc[i][j] = mfma16(af[i], bf[j], acc[i][j]);
  }
  int cc = ln & 15, rq = (ln >> 4) * 4;
  #pragma unroll
  for (int i = 0; i < 4; ++i)
    #pragma unroll
    for (int j = 0; j < 4; ++j) {
      int m = m0 + wr * 64 + i * 16 + rq;
      int v = n0 + wc * 64 + j * 16 + cc;
      float bv = bias[v];
      #pragma unroll
      for (int r2 = 0; r2 < 4; ++r2)
        if (m + r2 < 2056) out[(size_t)(m + r2) * 16384 + v] = f2bf(acc[i][j][r2] + bv);
    }
  if (bid == 2 * 17 * 128 - 1 && tid == 0) sb_set(sb, sbslot);
}

// ---------------- persistent bidirectional LSTM scan, weights in VGPRs ----------------
// 256 WGs x 512 thr. dir = wg>>7, wgd = wg&127 owns channels [wgd*32, +32).
// per step: gates = XW[t] + h@W_state (VGPR frags, MFMA); elementwise -> c,a;
// projection a@W_proj (VGPR frags, MFMA) -> f32 atomicAdd into rotating 3-buffer h_acc;
// ONE grid barrier per step.
__global__ __launch_bounds__(SCAN_THR, 2) void scan_kernel(
    const float* __restrict__ Wst_g, const float* __restrict__ Wp_g,
    const u16* __restrict__ XW, u16* __restrict__ sob_f, u16* __restrict__ sob_b,
    float* __restrict__ h_acc, int* __restrict__ bar, float* __restrict__ sb,
    int layer, int sbslot) {
  __shared__ u16 h_lds[4][520];          // stride 1040B
  __shared__ float gates_lds[4][32][4];  // [gate][chl][b]
  __shared__ u16 a_lds[4][40];           // stride 80B
  int tid = threadIdx.x, ln = tid & 63;
  int wv = tid >> 6;
  int l15 = ln & 15, lq = ln >> 4;
  int dir = (int)blockIdx.x >> 7, wgd = (int)blockIdx.x & 127;
  int dl = dir * 2 + layer;
  const float* Wst = Wst_g + (size_t)dl * 512 * 16384;
  const float* Wp  = Wp_g  + (size_t)dl * 4096 * 512;
  const u16* xw = XW + (size_t)dir * 2056 * 16384;
  u16* sob = dir ? sob_b : sob_f;
  float* hacc = h_acc + dir * 3 * 2048;

  // W_state frags: wave's WG-col = wv*16+l15 in [0,128) = gate(col>>5) x ch(col&31)
  int col = wv * 16 + l15;
  int gcol = (col >> 5) * 4096 + wgd * 32 + (col & 31);
  short8 wst[16];
  #pragma unroll
  for (int kt = 0; kt < 16; ++kt) {
    short8 f;
    #pragma unroll
    for (int e = 0; e < 8; ++e)
      ((u16*)&f)[e] = f2bf(Wst[(size_t)(kt * 32 + lq * 8 + e) * 16384 + gcol]);
    wst[kt] = f;
  }
  // W_proj frags: wave owns hcols [wv*64, +64); K = this WG's 32 channels
  short8 wpf[4];
  #pragma unroll
  for (int hct = 0; hct < 4; ++hct) {
    short8 f;
    #pragma unroll
    for (int e = 0; e < 8; ++e)
      ((u16*)&f)[e] =
          f2bf(Wp[(size_t)(wgd * 32 + lq * 8 + e) * 512 + wv * 64 + hct * 16 + l15]);
    wpf[hct] = f;
  }
  float cst = 0.f;                       // c-state (tid<128): ch=tid>>2, b=tid&3
  int ew_ch = tid >> 2, ew_b = tid & 3;

  for (int s = 0; s < TT; ++s) {
    int t = dir ? (TT - 1 - s) : s;
    // ---- stage h_{s-1} from hacc[s%3]: clip -> bf16 -> LDS (+ seq-out by wgd 0) ----
    {
      const float* hb = hacc + (s % 3) * 2048;
      int e0 = tid * 4;
      int b = e0 >> 9, d = e0 & 511;
      short4v pk;
      #pragma unroll
      for (int e = 0; e < 4; ++e) {
        float v = __hip_atomic_load(hb + e0 + e, __ATOMIC_RELAXED, __HIP_MEMORY_SCOPE_AGENT);
        v = fminf(3.f, fmaxf(-3.f, v));
        pk[e] = (short)f2bf(v);
      }
      *(short4v*)((char*)h_lds + b * 1040 + d * 2) = pk;
      if (wgd == 0 && s > 0) {
        int tp = dir ? (TT - s) : (s - 1);
        *(short4v*)(sob + ((size_t)tp * 4 + b) * 512 + d) = pk;
      }
    }
    // zero dead buffer (s+2)%3 (read at s-1, protected by last barrier)
    if (tid < 16)
      __hip_atomic_store(hacc + ((s + 2) % 3) * 2048 + wgd * 16 + tid, 0.f,
                         __ATOMIC_RELAXED, __HIP_MEMORY_SCOPE_AGENT);
    __syncthreads();
    // ---- gates MFMA: h @ W_state slice ----
    f32x4 acc = {0.f, 0.f, 0.f, 0.f};
    #pragma unroll
    for (int kt = 0; kt < 16; ++kt) {
      short8 hf = *(const short8*)((const char*)h_lds + (ln & 3) * 1040 + lq * 16 + kt * 64);
      acc = mfma16(hf, wst[kt], acc);
    }
    if (ln < 16) {   // D: col=lane&15, rows 0..3 = regs = batch
      #pragma unroll
      for (int r = 0; r < 4; ++r) gates_lds[col >> 5][col & 31][r] = acc[r];
    }
    __syncthreads();
    // ---- elementwise: gates + XW -> c update -> a ----
    if (tid < 128) {
      size_t xrow = ((size_t)t * 4 + ew_b) * 16384 + wgd * 32 + ew_ch;
      float gi = gates_lds[0][ew_ch][ew_b] + bf2f(xw[xrow]);
      float gf = gates_lds[1][ew_ch][ew_b] + bf2f(xw[xrow + 4096]);
      float gg = gates_lds[2][ew_ch][ew_b] + bf2f(xw[xrow + 8192]);
      float go = gates_lds[3][ew_ch][ew_b] + bf2f(xw[xrow + 12288]);
      float cn = sigm(gi) * tanhf(gg) + sigm(gf) * cst;
      cn = fminf(3.f, fmaxf(-3.f, cn));
      cst = cn;
      a_lds[ew_b][ew_ch] = f2bf(sigm(go) * tanhf(cn));
    }
    __syncthreads();
    // ---- projection: a[4x32] @ Wp[32x512] -> atomicAdd into hacc[(s+1)%3] ----
    short8 af = *(const short8*)((const char*)a_lds + (ln & 3) * 80 + lq * 16);
    f32x4 pacc[4];
    #pragma unroll
    for (int hct = 0; hct < 4; ++hct) {
      pacc[hct] = (f32x4){0.f, 0.f, 0.f, 0.f};
      pacc[hct] = mfma16(af, wpf[hct], pacc[hct]);
    }
    if (ln < 16) {
      float* ha = hacc + ((s + 1) % 3) * 2048;
      #pragma unroll
      for (int hh = 0; hh < 4; ++hh) {
        int hct = (hh + wgd) & 3;          // stagger to spread atomic contention
        #pragma unroll
        for (int r = 0; r < 4; ++r)
          atomicAdd(ha + r * 512 + wv * 64 + hct * 16 + l15, pacc[hct][r]);
      }
    }
    grid_barrier(bar);
  }
  // ---- final h (t = TT-1 fwd / 0 bwd) ----
  if (wgd == 0) {
    const float* hb = hacc + (TT % 3) * 2048;
    int e0 = tid * 4;
    int b = e0 >> 9, d = e0 & 511;
    short4v pk;
    #pragma unroll
    for (int e = 0; e < 4; ++e) {
      float v = __hip_atomic_load(hb + e0 + e, __ATOMIC_RELAXED, __HIP_MEMORY_SCOPE_AGENT);
      v = fminf(3.f, fmaxf(-3.f, v));
      pk[e] = (short)f2bf(v);
    }
    int tl = dir ? 0 : (TT - 1);
    *(short4v*)(sob + ((size_t)tl * 4 + b) * 512 + d) = pk;
  }
  __syncthreads();
  if ((int)blockIdx.x == SCAN_WGS - 1 && tid == 0) sb_set(sb, sbslot);
}

// ------- softmax-weight mixing -> f32 output + bf16 logit A (tied=[E;E] K-fold) -------
__global__ __launch_bounds__(256) void mix_kernel(const u16* __restrict__ xb,
                                                  const u16* __restrict__ s1f,
                                                  const u16* __restrict__ s1b,
                                                  const u16* __restrict__ s2f,
                                                  const u16* __restrict__ s2b,
                                                  const float* __restrict__ sv,
                                                  const float* __restrict__ gm,
                                                  float* __restrict__ out,
                                                  u16* __restrict__ logitA,
                                                  float* __restrict__ sb) {
  int m = blockIdx.x;             // b*512 + tt
  int b = m >> 9, tt = m & 511;
  int t = tt + 1;
  float v0s = sv[0], v1s = sv[1], v2s = sv[2];
  float mx = fmaxf(v0s, fmaxf(v1s, v2s));
  float e0 = expf(v0s - mx), e1 = expf(v1s - mx), e2 = expf(v2s - mx);
  float inv = 1.f / (e0 + e1 + e2);
  float w0 = e0 * inv, w1 = e1 * inv, w2 = e2 * inv;
  float g = gm[0];
  size_t base = ((size_t)t * 4 + b) * 512;
  for (int d = threadIdx.x; d < 512; d += 256) {
    float xv = bf2f(xb[base + d]);
    float a1f = bf2f(s1f[base + d]), a1b = bf2f(s1b[base + d]);
    float a2f = bf2f(s2f[base + d]), a2b = bf2f(s2b[base + d]);
    float o0 = g * (w0 * xv + w1 * a1f + w2 * (a2f + a1f));  // layer2 = raw + layer1 resid
    float o1 = g * (w0 * xv + w1 * a1b + w2 * (a2b + a1b));
    out[(size_t)m * 1024 + d] = o0;
    out[(size_t)m * 1024 + 512 + d] = o1;
    logitA[(size_t)m * 512 + d] = f2bf(o0 + o1);
  }
  if (m == 2047 && threadIdx.x == 0) sb_set(sb, 5);
}

__global__ __launch_bounds__(256) void mask_fill(float* __restrict__ out) {
  int i = blockIdx.x * 256 + threadIdx.x;
  if (i < 2048) out[2097152 + i] = 1.0f;
}

// ---- logit GEMM: C[2048][32000](f32) = A[2048][512](bf16) * E[32000][512](f32->bf16)^T ----
__global__ __launch_bounds__(256) void logit_gemm(const u16* __restrict__ A,
                                                  const float* __restrict__ E,
                                                  float* __restrict__ out) {
  int bid = blockIdx.x;
  int mb = bid / 250, nb = bid % 250;
  int m0 = mb * 128, n0 = nb * 128;
  __shared__ char lds[2 * 128 * 80];
  char* At = lds;
  char* Bt = lds + 128 * 80;
  int tid = threadIdx.x, wv = tid >> 6, ln = tid & 63;
  int wr = wv >> 1, wc = wv & 1;
  f32x4 acc[4][4];
  #pragma unroll
  for (int i = 0; i < 4; ++i)
    #pragma unroll
    for (int j = 0; j < 4; ++j) acc[i][j] = (f32x4){0.f, 0.f, 0.f, 0.f};
  for (int k0 = 0; k0 < 512; k0 += 32) {
    __syncthreads();
    int r = tid >> 2, kq = (tid & 3) * 8;
    for (int rr = r; rr < 128; rr += 64) {
      short8 va = *(const short8*)(A + (size_t)(m0 + rr) * 512 + k0 + kq);
      *(short8*)(At + rr * 80 + kq * 2) = va;
      const float* ep = E + (size_t)(n0 + rr) * 512 + k0 + kq;
      float4 ea = *(const float4*)ep;
      float4 eb = *(const float4*)(ep + 4);
      short8 vb;
      ((u16*)&vb)[0] = f2bf(ea.x); ((u16*)&vb)[1] = f2bf(ea.y);
      ((u16*)&vb)[2] = f2bf(ea.z); ((u16*)&vb)[3] = f2bf(ea.w);
      ((u16*)&vb)[4] = f2bf(eb.x); ((u16*)&vb)[5] = f2bf(eb.y);
      ((u16*)&vb)[6] = f2bf(eb.z); ((u16*)&vb)[7] = f2bf(eb.w);
      *(short8*)(Bt + rr * 80 + kq * 2) = vb;
    }
    __syncthreads();
    int lr = ln & 15, kq2 = (ln >> 4) * 8;
    short8 af[4], bf[4];
    #pragma unroll
    for (int i = 0; i < 4; ++i) {
      af[i] = *(const short8*)(At + (wr * 64 + i * 16 + lr) * 80 + kq2 * 2);
      bf[i] = *(const short8*)(Bt + (wc * 64 + i * 16 + lr) * 80 + kq2 * 2);
    }
    #pragma unroll
    for (int i = 0; i < 4; ++i)
      #pragma unroll
      for (int j = 0; j < 4; ++j) acc[i][j] = mfma16(af[i], bf[j], acc[i][j]);
  }
  int cc = ln & 15, rq = (ln >> 4) * 4;
  #pragma unroll
  for (int i = 0; i < 4; ++i)
    #pragma unroll
    for (int j = 0; j < 4; ++j) {
      int m = m0 + wr * 64 + i * 16 + rq;
      int v = n0 + wc * 64 + j * 16 + cc;
      #pragma unroll
      for (int r2 = 0; r2 < 4; ++r2)
        out[2099200 + (size_t)(m + r2) * 32000 + v] = acc[i][j][r2];
    }
}

static int map_hip_err(hipError_t e) {
  switch ((int)e) {
    case 1: return 1;
    case 2: return 2;
    case 9: return 3;
    case 98: return 4;
    case 701: return 5;
    case 719: return 6;
    case 720: return 7;
    default: return 0;
  }
}

extern "C" void kernel_launch(void* const* d_in, const int* in_sizes, int n_in,
                              void* d_out, int out_size, void* d_ws, size_t ws_size,
                              hipStream_t stream) {
  const int* words = (const int*)d_in[0];
  const float* E = (const float*)d_in[1];
  const float* bos = (const float*)d_in[2];
  const float* eos = (const float*)d_in[3];
  const float* Win = (const float*)d_in[4];
  const float* Wst = (const float*)d_in[5];
  const float* bias = (const float*)d_in[6];
  const float* Wp = (const float*)d_in[7];
  const float* sv = (const float*)d_in[8];
  const float* gm = (const float*)d_in[9];
  float* outp = (float*)d_out;

  // ---- input sanity ----
  {
    int bad = -1;
    if (n_in < 10) bad = 12;
    else {
      const int expct[10] = {2048, 16384000, 512, 512, 33554432, 33554432,
                             65536, 8388608, 3, 1};
      for (int i = 0; i < 10; ++i)
        if (in_sizes[i] != expct[i]) { bad = i; break; }
    }
    if (bad < 0 && out_size != 67635200) bad = 13;
    if (bad >= 0) {
      diag_kernel<<<1, 64, 0, stream>>>(outp, 40960.f + (float)bad * 256.f, 7);
      return;
    }
  }

  char* ws = (char*)d_ws;
  size_t off = 0;
  auto nxt = [&](size_t b) { size_t r = off; off += (b + 255) & ~(size_t)255; return r; };
  u16* xb16 = (u16*)(ws + nxt(514UL * 4 * 512 * 2));
  u16* s1fb = (u16*)(ws + nxt(514UL * 4 * 512 * 2));
  u16* s1bb = (u16*)(ws + nxt(514UL * 4 * 512 * 2));
  u16* s2fb = (u16*)(ws + nxt(514UL * 4 * 512 * 2));
  u16* s2bb = (u16*)(ws + nxt(514UL * 4 * 512 * 2));
  u16* logitA = (u16*)(ws + nxt(2048UL * 512 * 2));
  size_t hacc_off = nxt(2UL * 3 * 2048 * 4);           // 49152 B
  float* hacc = (float*)(ws + hacc_off);
  size_t bar_off = nxt(256);                           // bar0 @ +0, bar1 @ +64 (ints)
  int* bar0 = (int*)(ws + bar_off);
  int* bar1 = bar0 + 16;
  size_t sb_off = nxt(256);
  float* sb = (float*)(ws + sb_off);
  u16* XW = (u16*)(ws + nxt(2UL * 2056 * 16384 * 2));
  if (off > ws_size) {
    diag_kernel<<<1, 64, 0, stream>>>(outp, 49152.f, 7);
    return;
  }

  int errIdx = -1;
  hipError_t errE = hipSuccess;
  auto chk = [&](int idx) {
    hipError_t e = hipGetLastError();
    if (e != hipSuccess && errIdx < 0) { errIdx = idx; errE = e; }
  };

  hipMemsetAsync(ws + bar_off, 0, 512, stream);   // bar0+bar1+sb

  embed_kernel<<<TT * 4, 256, 0, stream>>>(words, E, bos, eos, xb16, sb);
  chk(0);

  // ================= layer 0 =================
  xw_gemm<<<2 * 17 * 128, 256, 0, stream>>>(xb16, xb16, Win, bias, XW, sb, 0, 1);
  chk(1);
  hipMemsetAsync(ws + hacc_off, 0, 49152, stream);
  scan_kernel<<<SCAN_WGS, SCAN_THR, 0, stream>>>(Wst, Wp, XW, s1fb, s1bb, hacc,
                                                 bar0, sb, 0, 2);
  chk(2);

  // ================= layer 1 =================
  xw_gemm<<<2 * 17 * 128, 256, 0, stream>>>(s1fb, s1bb, Win, bias, XW, sb, 1, 3);
  chk(3);
  hipMemsetAsync(ws + hacc_off, 0, 49152, stream);
  scan_kernel<<<SCAN_WGS, SCAN_THR, 0, stream>>>(Wst, Wp, XW, s2fb, s2bb, hacc,
                                                 bar1, sb, 1, 4);
  chk(4);

  mix_kernel<<<2048, 256, 0, stream>>>(xb16, s1fb, s1bb, s2fb, s2bb, sv, gm,
                                       outp, logitA, sb);
  chk(5);
  mask_fill<<<8, 256, 0, stream>>>(outp);
  chk(6);
  logit_gemm<<<4000, 256, 0, stream>>>(logitA, E, outp);
  chk(7);

  if (errIdx >= 0) {
    float code = 32768.f + (float)errIdx * 2048.f + (float)map_hip_err(errE) * 256.f;
    diag_kernel<<<1, 64, 0, stream>>>(outp, code, 7);
  }
  verify_kernel<<<1, 64, 0, stream>>>(sb, bar0, outp);
}

// Round 10
// 23662.276 us; speedup vs baseline: 4.8052x; 1.2146x over previous
//
#include <hip/hip_runtime.h>
#include <cstdint>
#include <cstddef>

#define TT 514
#define DIR_WGS 64
#define SCAN_WGS 128
#define SCAN_THR 512

typedef unsigned short u16;
typedef short short8 __attribute__((ext_vector_type(8)));
typedef float f32x4 __attribute__((ext_vector_type(4)));

__device__ __forceinline__ float bf2f(u16 u) {
  union { unsigned i; float f; } x; x.i = ((unsigned)u) << 16; return x.f;
}
__device__ __forceinline__ u16 f2bf(float f) {
  union { float f; unsigned i; } x; x.f = f;
  unsigned r = x.i + 0x7fffu + ((x.i >> 16) & 1u);
  return (u16)(r >> 16);
}
__device__ __forceinline__ float sigm(float x) { return 1.f / (1.f + expf(-x)); }
__device__ __forceinline__ f32x4 mfma16(short8 a, short8 b, f32x4 c) {
  return __builtin_amdgcn_mfma_f32_16x16x32_bf16(a, b, c, 0, 0, 0);
}
__device__ __forceinline__ void sb_set(float* sb, int k) {
  __hip_atomic_store(sb + k, 1.0f, __ATOMIC_RELAXED, __HIP_MEMORY_SCOPE_AGENT);
}

// per-dir sense-reversal barrier (64 arrivals), sticky dead-flag bailout
__device__ __forceinline__ void gbar(int* bar) {
  __syncthreads();
  if (threadIdx.x == 0) {
    if (__hip_atomic_load(bar + 2, __ATOMIC_RELAXED, __HIP_MEMORY_SCOPE_AGENT) == 0) {
      int g = __hip_atomic_load(bar + 1, __ATOMIC_RELAXED, __HIP_MEMORY_SCOPE_AGENT);
      int p = __hip_atomic_fetch_add(bar, 1, __ATOMIC_ACQ_REL, __HIP_MEMORY_SCOPE_AGENT);
      if (p == DIR_WGS - 1) {
        __hip_atomic_store(bar, 0, __ATOMIC_RELAXED, __HIP_MEMORY_SCOPE_AGENT);
        __hip_atomic_fetch_add(bar + 1, 1, __ATOMIC_RELEASE, __HIP_MEMORY_SCOPE_AGENT);
      } else {
        int spins = 0;
        while (__hip_atomic_load(bar + 1, __ATOMIC_ACQUIRE, __HIP_MEMORY_SCOPE_AGENT) == g) {
          __builtin_amdgcn_s_sleep(1);
          if (++spins > 10000000) {
            __hip_atomic_store(bar + 2, 1, __ATOMIC_RELAXED, __HIP_MEMORY_SCOPE_AGENT);
            break;
          }
        }
      }
    }
  }
  __syncthreads();
}

// ---- diagnostics (f32, visible) ----
__global__ void diag_kernel(float* __restrict__ out, float code, int slot) {
  if (threadIdx.x == 0 && blockIdx.x == 0) out[slot] = code;
}
__global__ void verify_kernel(const float* __restrict__ sb, const int* __restrict__ bars,
                              float* __restrict__ out) {
  if (threadIdx.x == 0 && blockIdx.x == 0) {
    for (int k = 0; k < 6; ++k) {
      float v = __hip_atomic_load(sb + k, __ATOMIC_RELAXED, __HIP_MEMORY_SCOPE_AGENT);
      if (v != 1.0f) out[9 + k] = 4096.f + (float)k * 256.f;
    }
    for (int slot = 0; slot < 4; ++slot)
      if (bars[slot * 64 + 2] != 0) out[8] = 8192.f + (float)slot * 256.f;
  }
}

// ---------------- embedding + BOS/EOS -> x bf16, layout [t][b][d] ----------------
__global__ __launch_bounds__(256) void embed_kernel(const int* __restrict__ words,
                                                    const float* __restrict__ E,
                                                    const float* __restrict__ bos,
                                                    const float* __restrict__ eos,
                                                    u16* __restrict__ xb16,
                                                    float* __restrict__ sb) {
  int bid = blockIdx.x;           // t*4 + b
  int t = bid >> 2, b = bid & 3;
  const float* src;
  if (t == 0) src = bos;
  else if (t == TT - 1) src = eos;
  else { int v = words[b * 512 + (t - 1)]; src = E + (size_t)v * 512; }
  for (int i = threadIdx.x; i < 512; i += 256)
    xb16[(size_t)bid * 512 + i] = f2bf(src[i]);
  if (bid == TT * 4 - 1 && threadIdx.x == 0) sb_set(sb, 0);
}

// ---- XW[dir][t*4+b][16384] = (x @ W_in + bias), bf16. K=512, M=2056, N=16384 ----
__global__ __launch_bounds__(256) void xw_gemm(const u16* __restrict__ Af,
                                               const u16* __restrict__ Ab,
                                               const float* __restrict__ Win_g,
                                               const float* __restrict__ bias_g,
                                               u16* __restrict__ XW,
                                               float* __restrict__ sb,
                                               int layer, int sbslot) {
  int bid = blockIdx.x;
  int dir = bid / (17 * 128);
  int rem = bid % (17 * 128);
  int mb = rem / 128, nb = rem % 128;
  const u16* A = dir ? Ab : Af;
  const float* B = Win_g + (size_t)(dir * 2 + layer) * 512 * 16384;
  const float* bias = bias_g + (size_t)(dir * 2 + layer) * 16384;
  u16* out = XW + (size_t)dir * 2056 * 16384;
  int m0 = mb * 128, n0 = nb * 128;
  __shared__ char lds[2 * 128 * 80];
  char* At = lds;
  char* Bt = lds + 128 * 80;
  int tid = threadIdx.x, wv = tid >> 6, ln = tid & 63;
  int wr = wv >> 1, wc = wv & 1;
  f32x4 acc[4][4];
  #pragma unroll
  for (int i = 0; i < 4; ++i)
    #pragma unroll
    for (int j = 0; j < 4; ++j) acc[i][j] = (f32x4){0.f, 0.f, 0.f, 0.f};
  for (int k0 = 0; k0 < 512; k0 += 32) {
    __syncthreads();
    {
      int r = tid >> 2, kq = (tid & 3) * 8;
      for (int rr = r; rr < 128; rr += 64) {
        int grow = m0 + rr; if (grow >= 2056) grow = 2055;
        short8 va = *(const short8*)(A + (size_t)grow * 512 + k0 + kq);
        *(short8*)(At + rr * 80 + kq * 2) = va;
      }
      int kk = tid >> 3, nq = (tid & 7) * 16;
      const float* bp = B + (size_t)(k0 + kk) * 16384 + n0 + nq;
      #pragma unroll
      for (int e = 0; e < 16; ++e)
        *(u16*)(Bt + (nq + e) * 80 + kk * 2) = f2bf(bp[e]);
    }
    __syncthreads();
    int lr = ln & 15, kq2 = (ln >> 4) * 8;
    short8 af[4], bf[4];
    #pragma unroll
    for (int i = 0; i < 4; ++i) {
      af[i] = *(const short8*)(At + (wr * 64 + i * 16 + lr) * 80 + kq2 * 2);
      bf[i] = *(const short8*)(Bt + (wc * 64 + i * 16 + lr) * 80 + kq2 * 2);
    }
    #pragma unroll
    for (int i = 0; i < 4; ++i)
      #pragma unroll
      for (int j = 0; j < 4; ++j) acc[i][j] = mfma16(af[i], bf[j], acc[i][j]);
  }
  int cc = ln & 15, rq = (ln >> 4) * 4;
  #pragma unroll
  for (int i = 0; i < 4; ++i)
    #pragma unroll
    for (int j = 0; j < 4; ++j) {
      int m = m0 + wr * 64 + i * 16 + rq;
      int v = n0 + wc * 64 + j * 16 + cc;
      float bv = bias[v];
      #pragma unroll
      for (int r2 = 0; r2 < 4; ++r2)
        if (m + r2 < 2056) out[(size_t)(m + r2) * 16384 + v] = f2bf(acc[i][j][r2] + bv);
    }
  if (bid == 2 * 17 * 128 - 1 && tid == 0) sb_set(sb, sbslot);
}

// ---------------- persistent bidirectional LSTM scan v10 ----------------
// 128 WGs x 512 thr. dir = wg>>6, wgd = wg&63 owns channels [wgd*64,+64) AND h-cols [wgd*8,+8).
// per step: h-broadcast -> gates MFMA (wst VGPR) -> elementwise -> a-broadcast -> B1 ->
//           full-K projection for own 8 h-cols (wpf VGPR, no atomic contention) -> B2.
__global__ __launch_bounds__(SCAN_THR, 2) void scan_kernel(
    const float* __restrict__ Wst_g, const float* __restrict__ Wp_g,
    const u16* __restrict__ XW, u16* __restrict__ sob_f, u16* __restrict__ sob_b,
    unsigned* __restrict__ hbuf, unsigned* __restrict__ abuf,
    int* __restrict__ bar, float* __restrict__ sb, int layer, int sbslot) {
  __shared__ u16 h_lds[4][520];          // stride 1040 B
  __shared__ u16 a_full[4][4104];        // stride 8208 B
  __shared__ float gates_lds[256][4];    // [col][b]
  __shared__ float red[8][8][4];         // [wave][col][b]
  __shared__ u16 hh[4][8];               // [b][col] bf16
  __shared__ u16 a_loc[4][64];           // [b][ch]
  int tid = threadIdx.x, ln = tid & 63;
  int wv = tid >> 6, l15 = ln & 15, lq = ln >> 4;
  int dir = (int)blockIdx.x >> 6, wgd = (int)blockIdx.x & 63;
  int dl = dir * 2 + layer;
  const float* Wst = Wst_g + (size_t)dl * 512 * 16384;
  const float* Wp  = Wp_g  + (size_t)dl * 4096 * 512;
  const u16* xw = XW + (size_t)dir * 2056 * 16384;
  u16* sob = dir ? sob_b : sob_f;
  unsigned* hb = hbuf + dir * 1024;
  unsigned* ab = abuf + dir * 8192;
  int* mybar = bar + dir * 64;

  // W_state frags: 2 col-tiles x 16 k-tiles (this WG's 256 gate-cols)
  short8 wst[2][16];
  #pragma unroll
  for (int ct = 0; ct < 2; ++ct) {
    int colL = wv * 32 + ct * 16 + l15;
    int gcol = (colL >> 6) * 4096 + wgd * 64 + (colL & 63);
    #pragma unroll
    for (int kt = 0; kt < 16; ++kt) {
      short8 f;
      #pragma unroll
      for (int e = 0; e < 8; ++e)
        ((u16*)&f)[e] = f2bf(Wst[(size_t)(kt * 32 + lq * 8 + e) * 16384 + gcol]);
      wst[ct][kt] = f;
    }
  }
  // W_proj frags: 16 k-tiles (wave wv covers k in [wv*512, +512)), 8 real cols
  short8 wpf[16];
  #pragma unroll
  for (int i = 0; i < 16; ++i) {
    short8 f;
    #pragma unroll
    for (int e = 0; e < 8; ++e) {
      int k = (wv * 16 + i) * 32 + lq * 8 + e;
      ((u16*)&f)[e] = (l15 < 8) ? f2bf(Wp[(size_t)k * 512 + wgd * 8 + l15]) : (u16)0;
    }
    wpf[i] = f;
  }
  float cst = 0.f;                       // c-state (tid<256): ch=tid>>2, b=tid&3
  int ew_ch = tid >> 2, ew_b = tid & 3;

  for (int s = 0; s < TT; ++s) {
    int t = dir ? (TT - 1 - s) : s;
    // ---- phase 1: h broadcast load (packed bf16x2) -> LDS ----
    #pragma unroll
    for (int i = tid; i < 1024; i += SCAN_THR) {
      unsigned v = __hip_atomic_load(hb + i, __ATOMIC_RELAXED, __HIP_MEMORY_SCOPE_AGENT);
      *(unsigned*)((char*)h_lds + (i >> 8) * 1040 + (i & 255) * 4) = v;
    }
    __syncthreads();
    // ---- phase 2: gates MFMA ----
    f32x4 g0 = {0.f, 0.f, 0.f, 0.f}, g1 = {0.f, 0.f, 0.f, 0.f};
    #pragma unroll
    for (int kt = 0; kt < 16; ++kt) {
      short8 hf = *(const short8*)((const char*)h_lds + (ln & 3) * 1040 + lq * 16 + kt * 64);
      g0 = mfma16(hf, wst[0][kt], g0);
      g1 = mfma16(hf, wst[1][kt], g1);
    }
    if (ln < 16) {
      #pragma unroll
      for (int r = 0; r < 4; ++r) {
        gates_lds[wv * 32 + l15][r] = g0[r];
        gates_lds[wv * 32 + 16 + l15][r] = g1[r];
      }
    }
    __syncthreads();
    // ---- phase 3: elementwise -> a ----
    if (tid < 256) {
      size_t xbase = ((size_t)t * 4 + ew_b) * 16384 + wgd * 64 + ew_ch;
      float gi = gates_lds[0 * 64 + ew_ch][ew_b] + bf2f(xw[xbase]);
      float gf = gates_lds[1 * 64 + ew_ch][ew_b] + bf2f(xw[xbase + 4096]);
      float gg = gates_lds[2 * 64 + ew_ch][ew_b] + bf2f(xw[xbase + 8192]);
      float go = gates_lds[3 * 64 + ew_ch][ew_b] + bf2f(xw[xbase + 12288]);
      float cn = sigm(gi) * tanhf(gg) + sigm(gf) * cst;
      cn = fminf(3.f, fmaxf(-3.f, cn));
      cst = cn;
      a_loc[ew_b][ew_ch] = f2bf(sigm(go) * tanhf(cn));
    }
    __syncthreads();
    if (tid < 128) {   // pack a -> global (uncontended)
      int b = tid >> 5, j = tid & 31;
      unsigned lo = a_loc[b][j * 2], hi = a_loc[b][j * 2 + 1];
      __hip_atomic_store(ab + b * 2048 + wgd * 32 + j, lo | (hi << 16),
                         __ATOMIC_RELAXED, __HIP_MEMORY_SCOPE_AGENT);
    }
    gbar(mybar);   // B1: all a visible
    // ---- phase 5: a broadcast load -> LDS ----
    #pragma unroll
    for (int i = tid; i < 8192; i += SCAN_THR) {
      unsigned v = __hip_atomic_load(ab + i, __ATOMIC_RELAXED, __HIP_MEMORY_SCOPE_AGENT);
      *(unsigned*)((char*)a_full + (i >> 11) * 8208 + (i & 2047) * 4) = v;
    }
    __syncthreads();
    // ---- phase 6: projection (own 8 h-cols, full K=4096) ----
    f32x4 p = {0.f, 0.f, 0.f, 0.f};
    #pragma unroll
    for (int i = 0; i < 16; ++i) {
      short8 af = *(const short8*)((const char*)a_full + (ln & 3) * 8208 + lq * 16 +
                                   (wv * 16 + i) * 64);
      p = mfma16(af, wpf[i], p);
    }
    if (ln < 8) {
      #pragma unroll
      for (int r = 0; r < 4; ++r) red[wv][ln][r] = p[r];
    }
    __syncthreads();
    if (tid < 32) {    // cross-wave reduce + clip + seq-out
      int col = tid >> 2, b = tid & 3;
      float v = 0.f;
      #pragma unroll
      for (int w = 0; w < 8; ++w) v += red[w][col][b];
      v = fminf(3.f, fmaxf(-3.f, v));
      u16 hv = f2bf(v);
      hh[b][col] = hv;
      sob[((size_t)t * 4 + b) * 512 + wgd * 8 + col] = hv;
    }
    __syncthreads();
    if (tid < 16) {    // pack h -> global (uncontended)
      int b = tid >> 2, j = tid & 3;
      unsigned lo = hh[b][j * 2], hi = hh[b][j * 2 + 1];
      __hip_atomic_store(hb + b * 256 + wgd * 4 + j, lo | (hi << 16),
                         __ATOMIC_RELAXED, __HIP_MEMORY_SCOPE_AGENT);
    }
    gbar(mybar);   // B2: h(s) visible
  }
  if ((int)blockIdx.x == SCAN_WGS - 1 && tid == 0) sb_set(sb, sbslot);
}

// ------- softmax-weight mixing -> f32 output + bf16 logit A (tied=[E;E] K-fold) -------
__global__ __launch_bounds__(256) void mix_kernel(const u16* __restrict__ xb,
                                                  const u16* __restrict__ s1f,
                                                  const u16* __restrict__ s1b,
                                                  const u16* __restrict__ s2f,
                                                  const u16* __restrict__ s2b,
                                                  const float* __restrict__ sv,
                                                  const float* __restrict__ gm,
                                                  float* __restrict__ out,
                                                  u16* __restrict__ logitA,
                                                  float* __restrict__ sb) {
  int m = blockIdx.x;             // b*512 + tt
  int b = m >> 9, tt = m & 511;
  int t = tt + 1;
  float v0s = sv[0], v1s = sv[1], v2s = sv[2];
  float mx = fmaxf(v0s, fmaxf(v1s, v2s));
  float e0 = expf(v0s - mx), e1 = expf(v1s - mx), e2 = expf(v2s - mx);
  float inv = 1.f / (e0 + e1 + e2);
  float w0 = e0 * inv, w1 = e1 * inv, w2 = e2 * inv;
  float g = gm[0];
  size_t base = ((size_t)t * 4 + b) * 512;
  for (int d = threadIdx.x; d < 512; d += 256) {
    float xv = bf2f(xb[base + d]);
    float a1f = bf2f(s1f[base + d]), a1b = bf2f(s1b[base + d]);
    float a2f = bf2f(s2f[base + d]), a2b = bf2f(s2b[base + d]);
    float o0 = g * (w0 * xv + w1 * a1f + w2 * (a2f + a1f));  // layer2 = raw + layer1 resid
    float o1 = g * (w0 * xv + w1 * a1b + w2 * (a2b + a1b));
    out[(size_t)m * 1024 + d] = o0;
    out[(size_t)m * 1024 + 512 + d] = o1;
    logitA[(size_t)m * 512 + d] = f2bf(o0 + o1);
  }
  if (m == 2047 && threadIdx.x == 0) sb_set(sb, 5);
}

__global__ __launch_bounds__(256) void mask_fill(float* __restrict__ out) {
  int i = blockIdx.x * 256 + threadIdx.x;
  if (i < 2048) out[2097152 + i] = 1.0f;
}

// ---- logit GEMM: C[2048][32000](f32) = A[2048][512](bf16) * E[32000][512](f32->bf16)^T ----
__global__ __launch_bounds__(256) void logit_gemm(const u16* __restrict__ A,
                                                  const float* __restrict__ E,
                                                  float* __restrict__ out) {
  int bid = blockIdx.x;
  int mb = bid / 250, nb = bid % 250;
  int m0 = mb * 128, n0 = nb * 128;
  __shared__ char lds[2 * 128 * 80];
  char* At = lds;
  char* Bt = lds + 128 * 80;
  int tid = threadIdx.x, wv = tid >> 6, ln = tid & 63;
  int wr = wv >> 1, wc = wv & 1;
  f32x4 acc[4][4];
  #pragma unroll
  for (int i = 0; i < 4; ++i)
    #pragma unroll
    for (int j = 0; j < 4; ++j) acc[i][j] = (f32x4){0.f, 0.f, 0.f, 0.f};
  for (int k0 = 0; k0 < 512; k0 += 32) {
    __syncthreads();
    int r = tid >> 2, kq = (tid & 3) * 8;
    for (int rr = r; rr < 128; rr += 64) {
      short8 va = *(const short8*)(A + (size_t)(m0 + rr) * 512 + k0 + kq);
      *(short8*)(At + rr * 80 + kq * 2) = va;
      const float* ep = E + (size_t)(n0 + rr) * 512 + k0 + kq;
      float4 ea = *(const float4*)ep;
      float4 eb = *(const float4*)(ep + 4);
      short8 vb;
      ((u16*)&vb)[0] = f2bf(ea.x); ((u16*)&vb)[1] = f2bf(ea.y);
      ((u16*)&vb)[2] = f2bf(ea.z); ((u16*)&vb)[3] = f2bf(ea.w);
      ((u16*)&vb)[4] = f2bf(eb.x); ((u16*)&vb)[5] = f2bf(eb.y);
      ((u16*)&vb)[6] = f2bf(eb.z); ((u16*)&vb)[7] = f2bf(eb.w);
      *(short8*)(Bt + rr * 80 + kq * 2) = vb;
    }
    __syncthreads();
    int lr = ln & 15, kq2 = (ln >> 4) * 8;
    short8 af[4], bf[4];
    #pragma unroll
    for (int i = 0; i < 4; ++i) {
      af[i] = *(const short8*)(At + (wr * 64 + i * 16 + lr) * 80 + kq2 * 2);
      bf[i] = *(const short8*)(Bt + (wc * 64 + i * 16 + lr) * 80 + kq2 * 2);
    }
    #pragma unroll
    for (int i = 0; i < 4; ++i)
      #pragma unroll
      for (int j = 0; j < 4; ++j) acc[i][j] = mfma16(af[i], bf[j], acc[i][j]);
  }
  int cc = ln & 15, rq = (ln >> 4) * 4;
  #pragma unroll
  for (int i = 0; i < 4; ++i)
    #pragma unroll
    for (int j = 0; j < 4; ++j) {
      int m = m0 + wr * 64 + i * 16 + rq;
      int v = n0 + wc * 64 + j * 16 + cc;
      #pragma unroll
      for (int r2 = 0; r2 < 4; ++r2)
        out[2099200 + (size_t)(m + r2) * 32000 + v] = acc[i][j][r2];
    }
}

static int map_hip_err(hipError_t e) {
  switch ((int)e) {
    case 1: return 1;
    case 2: return 2;
    case 9: return 3;
    case 98: return 4;
    case 701: return 5;
    case 719: return 6;
    case 720: return 7;
    default: return 0;
  }
}

extern "C" void kernel_launch(void* const* d_in, const int* in_sizes, int n_in,
                              void* d_out, int out_size, void* d_ws, size_t ws_size,
                              hipStream_t stream) {
  const int* words = (const int*)d_in[0];
  const float* E = (const float*)d_in[1];
  const float* bos = (const float*)d_in[2];
  const float* eos = (const float*)d_in[3];
  const float* Win = (const float*)d_in[4];
  const float* Wst = (const float*)d_in[5];
  const float* bias = (const float*)d_in[6];
  const float* Wp = (const float*)d_in[7];
  const float* sv = (const float*)d_in[8];
  const float* gm = (const float*)d_in[9];
  float* outp = (float*)d_out;

  // ---- input sanity ----
  {
    int bad = -1;
    if (n_in < 10) bad = 12;
    else {
      const int expct[10] = {2048, 16384000, 512, 512, 33554432, 33554432,
                             65536, 8388608, 3, 1};
      for (int i = 0; i < 10; ++i)
        if (in_sizes[i] != expct[i]) { bad = i; break; }
    }
    if (bad < 0 && out_size != 67635200) bad = 13;
    if (bad >= 0) {
      diag_kernel<<<1, 64, 0, stream>>>(outp, 40960.f + (float)bad * 256.f, 7);
      return;
    }
  }

  char* ws = (char*)d_ws;
  size_t off = 0;
  auto nxt = [&](size_t b) { size_t r = off; off += (b + 255) & ~(size_t)255; return r; };
  u16* xb16 = (u16*)(ws + nxt(514UL * 4 * 512 * 2));
  u16* s1fb = (u16*)(ws + nxt(514UL * 4 * 512 * 2));
  u16* s1bb = (u16*)(ws + nxt(514UL * 4 * 512 * 2));
  u16* s2fb = (u16*)(ws + nxt(514UL * 4 * 512 * 2));
  u16* s2bb = (u16*)(ws + nxt(514UL * 4 * 512 * 2));
  u16* logitA = (u16*)(ws + nxt(2048UL * 512 * 2));
  size_t hbuf_off = nxt(2UL * 1024 * 4);               // 8 KB packed bf16x2
  unsigned* hbuf = (unsigned*)(ws + hbuf_off);
  unsigned* abuf = (unsigned*)(ws + nxt(2UL * 8192 * 4));  // 64 KB packed bf16x2
  size_t bar_off = nxt(4UL * 64 * 4);                  // 4 slots (layer,dir) x 64 ints
  int* bars = (int*)(ws + bar_off);
  size_t sb_off = nxt(256);
  float* sb = (float*)(ws + sb_off);
  u16* XW = (u16*)(ws + nxt(2UL * 2056 * 16384 * 2));
  if (off > ws_size) {
    diag_kernel<<<1, 64, 0, stream>>>(outp, 49152.f, 7);
    return;
  }

  int errIdx = -1;
  hipError_t errE = hipSuccess;
  auto chk = [&](int idx) {
    hipError_t e = hipGetLastError();
    if (e != hipSuccess && errIdx < 0) { errIdx = idx; errE = e; }
  };

  hipMemsetAsync(ws + bar_off, 0, 4 * 64 * 4 + 256 + 256, stream);  // bars + sb

  embed_kernel<<<TT * 4, 256, 0, stream>>>(words, E, bos, eos, xb16, sb);
  chk(0);

  // ================= layer 0 =================
  xw_gemm<<<2 * 17 * 128, 256, 0, stream>>>(xb16, xb16, Win, bias, XW, sb, 0, 1);
  chk(1);
  hipMemsetAsync(ws + hbuf_off, 0, 2 * 1024 * 4, stream);
  scan_kernel<<<SCAN_WGS, SCAN_THR, 0, stream>>>(Wst, Wp, XW, s1fb, s1bb, hbuf, abuf,
                                                 bars, sb, 0, 2);
  chk(2);

  // ================= layer 1 =================
  xw_gemm<<<2 * 17 * 128, 256, 0, stream>>>(s1fb, s1bb, Win, bias, XW, sb, 1, 3);
  chk(3);
  hipMemsetAsync(ws + hbuf_off, 0, 2 * 1024 * 4, stream);
  scan_kernel<<<SCAN_WGS, SCAN_THR, 0, stream>>>(Wst, Wp, XW, s2fb, s2bb, hbuf, abuf,
                                                 bars + 128, sb, 1, 4);
  chk(4);

  mix_kernel<<<2048, 256, 0, stream>>>(xb16, s1fb, s1bb, s2fb, s2bb, sv, gm,
                                       outp, logitA, sb);
  chk(5);
  mask_fill<<<8, 256, 0, stream>>>(outp);
  chk(6);
  logit_gemm<<<4000, 256, 0, stream>>>(logitA, E, outp);
  chk(7);

  if (errIdx >= 0) {
    float code = 32768.f + (float)errIdx * 2048.f + (float)map_hip_err(errE) * 256.f;
    diag_kernel<<<1, 64, 0, stream>>>(outp, code, 7);
  }
  verify_kernel<<<1, 64, 0, stream>>>(sb, bars, outp);
}